// Round 7
// baseline (118.815 us; speedup 1.0000x reference)
//
#include <hip/hip_runtime.h>

typedef _Float16 f16x8 __attribute__((ext_vector_type(8)));
typedef float f32x4 __attribute__((ext_vector_type(4)));

#define HDIM  128
#define NSTEP 64
#define NG    512   // 4H gate columns
#define BPB   16    // batches per block (MFMA M)

__device__ __forceinline__ float sigf(float x) {
    return __builtin_amdgcn_rcpf(1.f + __expf(-x));
}
__device__ __forceinline__ float tanhfast(float x) {
    return fmaf(2.f, __builtin_amdgcn_rcpf(1.f + __expf(-2.f * x)), -1.f);
}
__device__ __forceinline__ unsigned int packh2(float a, float b) {
    union { _Float16 h[2]; unsigned int u; } x;
    x.h[0] = (_Float16)a; x.h[1] = (_Float16)b; return x.u;
}

__global__ __launch_bounds__(256) void copy_trip_k(const float4* __restrict__ src,
                                                   float4* __restrict__ dst) {
    int i = blockIdx.x * 256 + threadIdx.x;   // 65536 float4 total
    dst[i] = src[i];
}

// grid = 4 blocks x 512 threads (8 waves). Block owns 16 batches.
// Wave w owns gate tiles {w, 8+w, 16+w, 24+w} = gates f,i,o,cand for
// h in [16w, 16w+16): after MFMA, the LSTM update is WAVE-LOCAL (no gate
// exchange through LDS, one barrier/step). W frags pinned in AGPRs.
__global__ __launch_bounds__(512, 2) void recur_k(
    const float* __restrict__ emb, const float* __restrict__ Wg,
    const float* __restrict__ bg,  float* __restrict__ outb) {
    __shared__ __align__(16) unsigned short state_s[2][BPB * 256]; // f16 [c|h]/batch, XOR-swz, 2x8KB

    const int blk = blockIdx.x, t = threadIdx.x;
    const int w = t >> 6, l = t & 63;
    const int lg = l >> 4, lr = l & 15;     // k-group, row-in-tile
    const int h = w * 16 + lr;              // h index this thread updates

    // ---- B-fragments + bias (one-time). col = i*128 + h; k = kt*32+lg*8+e
    // (same k-map as A below; MFMA dot invariant under common k-permutation). ----
    f16x8 B[4][8];
    float bgc[4];
    #pragma unroll
    for (int i = 0; i < 4; ++i) {
        const int c = i * 128 + h;
        bgc[i] = bg[c];
        #pragma unroll
        for (int kt = 0; kt < 8; ++kt) {
            f16x8 v;
            #pragma unroll
            for (int e = 0; e < 8; ++e)
                v[e] = (_Float16)Wg[(kt * 32 + lg * 8 + e) * NG + c];
            B[i][kt] = v;
        }
    }
    #pragma unroll
    for (int i = 0; i < 4; ++i)
        #pragma unroll
        for (int kt = 0; kt < 8; ++kt)
            asm volatile("" : "+a"(B[i][kt]));   // pin W resident in AGPRs

    // ---- initial state buf0: [c=emb_row0 | h=0] f16, XOR-swizzled rows ----
    for (int wd = t; wd < BPB * 128; wd += 512) {
        int batch = wd >> 7, kw = wd & 127;      // word = halves k=2kw,2kw+1
        unsigned int val = 0u;
        if (kw < 64) {
            const float* e2 = emb + (size_t)(blk * BPB + batch) * 64 * HDIM + 2 * kw;
            val = packh2(e2[0], e2[1]);
        }
        *(unsigned int*)((char*)state_s[0] + batch * 512 + ((kw * 4) ^ ((batch & 7) << 4))) = val;
    }
    float c[4] = {0.f, 0.f, 0.f, 0.f};   // c[batch=lg*4+q][h], c0 = 0
    float ph[4];                          // prev-step c, stored next step (pipelined)
    __syncthreads();

    for (int s = 0; s < NSTEP; ++s) {
        // ---- pipelined history store: prev step's c, hidden under MFMA ----
        if (s > 0) {
            #pragma unroll
            for (int q = 0; q < 4; ++q)
                outb[(size_t)(blk * BPB + lg * 4 + q) * 65536 + (s - 1) * 1024 + h] = ph[q];
        }
        // ---- MFMA phase: acc[i] = gates tile (i*8+w), rows=batches ----
        f32x4 acc[4];
        #pragma unroll
        for (int i = 0; i < 4; ++i) acc[i] = (f32x4){bgc[i], bgc[i], bgc[i], bgc[i]};
        const char* buf = (const char*)state_s[s & 1];
        #pragma unroll
        for (int kt = 0; kt < 8; ++kt) {
            f16x8 a8 = *(const f16x8*)(buf + lr * 512 + ((kt * 64 + lg * 16) ^ ((lr & 7) << 4)));
            #pragma unroll
            for (int i = 0; i < 4; ++i)
                acc[i] = __builtin_amdgcn_mfma_f32_16x16x32_f16(a8, B[i][kt], acc[i], 0, 0, 0);
        }
        // ---- wave-local update: thread owns (batch=lg*4+q, h), q=0..3 ----
        char* bufn = (char*)state_s[(s + 1) & 1];
        #pragma unroll
        for (int q = 0; q < 4; ++q) {
            float F = sigf(acc[0][q]);
            float I = sigf(acc[1][q]);
            float O = sigf(acc[2][q]);
            float Dd = tanhfast(acc[3][q]);
            float cn = fmaf(F, c[q], I * Dd);
            float hn = O * tanhfast(cn);
            c[q] = cn; ph[q] = cn;
            // pack (h, h+1) pairs via neighbor lane; even-lr lanes store u32
            float co = __shfl_xor(cn, 1);
            float ho = __shfl_xor(hn, 1);
            if (!(lr & 1)) {
                const int batch = lg * 4 + q;
                char* bb = bufn + batch * 512;
                *(unsigned int*)(bb + ((2 * h) ^ ((batch & 7) << 4)))       = packh2(cn, co);
                *(unsigned int*)(bb + ((256 + 2 * h) ^ ((batch & 7) << 4))) = packh2(hn, ho);
            }
        }
        __syncthreads();
    }
    // ---- flush last step's history ----
    #pragma unroll
    for (int q = 0; q < 4; ++q)
        outb[(size_t)(blk * BPB + lg * 4 + q) * 65536 + 63 * 1024 + h] = ph[q];
}

// 4096 blocks (b*64+s) x 256 threads. recur stashed c[b][s][0:128] in the first
// 512 B of this block's OWN 4 KB output region; read it, project, then overwrite
// the region with the projected row replicated 64x. No cross-block hazard.
__global__ __launch_bounds__(256) void proj_expand_k(const float* __restrict__ Wl,
                                                     const float* __restrict__ bl,
                                                     float* __restrict__ outb) {
    __shared__ float c_s[HDIM];
    __shared__ __align__(16) float pj[16];
    const int bs = blockIdx.x, t = threadIdx.x;
    float* reg = outb + (size_t)bs * 1024;
    if (t < HDIM) c_s[t] = reg[t];
    __syncthreads();
    if (t < 16) {
        float a = bl[t];
        #pragma unroll 16
        for (int h = 0; h < HDIM; ++h) a = fmaf(c_s[h], Wl[h * 16 + t], a);
        pj[t] = a;
    }
    __syncthreads();
    float4 v = ((const float4*)pj)[t & 3];
    ((float4*)reg)[t] = v;   // 256 float4 = 64 rows x 16 floats
}

extern "C" void kernel_launch(void* const* d_in, const int* in_sizes, int n_in,
                              void* d_out, int out_size, void* d_ws, size_t ws_size,
                              hipStream_t stream) {
    const float* trip = (const float*)d_in[0];
    // d_in[1] = valid_len : unused by the reference computation
    const float* emb  = (const float*)d_in[2];
    const float* Wg   = (const float*)d_in[3];
    const float* bgp  = (const float*)d_in[4];
    const float* Wlp  = (const float*)d_in[5];
    const float* blp  = (const float*)d_in[6];
    float* out = (float*)d_out;

    // output = [trip (262144 floats) | big (4194304 floats)]
    copy_trip_k<<<256, 256, 0, stream>>>((const float4*)trip, (float4*)out);
    recur_k<<<4, 512, 0, stream>>>(emb, Wg, bgp, out + 262144);
    proj_expand_k<<<4096, 256, 0, stream>>>(Wlp, blp, out + 262144);
}

// Round 8
// 113.063 us; speedup vs baseline: 1.0509x; 1.0509x over previous
//
#include <hip/hip_runtime.h>

typedef _Float16 f16x8 __attribute__((ext_vector_type(8)));
typedef float f32x4 __attribute__((ext_vector_type(4)));

#define HDIM  128
#define NSTEP 64
#define NG    512   // 4H gate columns
#define BPB   16    // batches per block (MFMA M)

__device__ __forceinline__ float sigf(float x) {
    return __builtin_amdgcn_rcpf(1.f + __expf(-x));
}
__device__ __forceinline__ float tanhfast(float x) {
    return fmaf(2.f, __builtin_amdgcn_rcpf(1.f + __expf(-2.f * x)), -1.f);
}
__device__ __forceinline__ unsigned int packh2(float a, float b) {
    union { _Float16 h[2]; unsigned int u; } x;
    x.h[0] = (_Float16)a; x.h[1] = (_Float16)b; return x.u;
}

__global__ __launch_bounds__(256) void copy_trip_k(const float4* __restrict__ src,
                                                   float4* __restrict__ dst) {
    int i = blockIdx.x * 256 + threadIdx.x;   // 65536 float4 total
    dst[i] = src[i];
}

// grid = 4 blocks x 512 threads (8 waves). Block owns 16 batches.
// Wave w owns gate tiles {w, 8+w, 16+w, 24+w} = f,i,o,cand for h in
// [16w,16w+16): LSTM update is wave-local, one barrier/step.
// W fragments live in AGPRs and are consumed NATIVELY by asm MFMA ("a"
// constraint) -- no v_accvgpr_read copies in the loop.
__global__ __launch_bounds__(512, 2) void recur_k(
    const float* __restrict__ emb, const float* __restrict__ Wg,
    const float* __restrict__ bg,  float* __restrict__ outb) {
    __shared__ __align__(16) unsigned short state_s[2][BPB * 256]; // f16 [c|h]/batch, XOR-swz, 2x8KB

    const int blk = blockIdx.x, t = threadIdx.x;
    const int w = t >> 6, l = t & 63;
    const int lg = l >> 4, lr = l & 15;     // k-group, row-in-tile
    const int h = w * 16 + lr;              // h index this thread updates

    // ---- B-fragments + bias (one-time). col = i*128 + h; k = kt*32+lg*8+e
    // (same k-map as A below; MFMA dot invariant under common k-permutation). ----
    f16x8 B[4][8];
    float bgc[4];
    #pragma unroll
    for (int i = 0; i < 4; ++i) {
        const int c = i * 128 + h;
        bgc[i] = bg[c];
        #pragma unroll
        for (int kt = 0; kt < 8; ++kt) {
            f16x8 v;
            #pragma unroll
            for (int e = 0; e < 8; ++e)
                v[e] = (_Float16)Wg[(kt * 32 + lg * 8 + e) * NG + c];
            B[i][kt] = v;
        }
    }
    #pragma unroll
    for (int i = 0; i < 4; ++i)
        #pragma unroll
        for (int kt = 0; kt < 8; ++kt)
            asm volatile("" : "+a"(B[i][kt]));   // materialize W in AGPRs now

    // ---- initial state buf0: [c=emb_row0 | h=0] f16, XOR-swizzled rows ----
    for (int wd = t; wd < BPB * 128; wd += 512) {
        int batch = wd >> 7, kw = wd & 127;      // word = halves k=2kw,2kw+1
        unsigned int val = 0u;
        if (kw < 64) {
            const float* e2 = emb + (size_t)(blk * BPB + batch) * 64 * HDIM + 2 * kw;
            val = packh2(e2[0], e2[1]);
        }
        *(unsigned int*)((char*)state_s[0] + batch * 512 + ((kw * 4) ^ ((batch & 7) << 4))) = val;
    }
    float c[4] = {0.f, 0.f, 0.f, 0.f};   // c[batch=lg*4+q][h], c0 = 0
    float ph[4];                          // prev-step c, stored next step
    float* hp[4];                         // running history pointers (+1024/step)
    #pragma unroll
    for (int q = 0; q < 4; ++q)
        hp[q] = outb + (size_t)(blk * BPB + lg * 4 + q) * 65536 + h;
    __syncthreads();

    for (int s = 0; s < NSTEP; ++s) {
        // ---- pipelined history store: prev step's c, hidden under MFMA ----
        if (s > 0) {
            #pragma unroll
            for (int q = 0; q < 4; ++q) { hp[q][0] = ph[q]; hp[q] += 1024; }
        }
        // ---- preload all 8 A-fragments (batch-rows), one wait-batch ----
        const char* buf = (const char*)state_s[s & 1];
        f16x8 a8[8];
        #pragma unroll
        for (int kt = 0; kt < 8; ++kt)
            a8[kt] = *(const f16x8*)(buf + lr * 512 + ((kt * 64 + lg * 16) ^ ((lr & 7) << 4)));
        // ---- MFMA: acc[i] = gate tile (i*8+w); B straight from AGPRs ----
        f32x4 acc[4];
        #pragma unroll
        for (int i = 0; i < 4; ++i) acc[i] = (f32x4){bgc[i], bgc[i], bgc[i], bgc[i]};
        #pragma unroll
        for (int kt = 0; kt < 8; ++kt) {
            #pragma unroll
            for (int i = 0; i < 4; ++i)
                asm("v_mfma_f32_16x16x32_f16 %0, %1, %2, %0"
                    : "+v"(acc[i]) : "v"(a8[kt]), "a"(B[i][kt]));
        }
        // ---- wave-local update: thread owns (batch=lg*4+q, h), q=0..3 ----
        char* bufn = (char*)state_s[(s + 1) & 1];
        #pragma unroll
        for (int q = 0; q < 4; ++q) {
            float F = sigf(acc[0][q]);
            float I = sigf(acc[1][q]);
            float O = sigf(acc[2][q]);
            float Dd = tanhfast(acc[3][q]);
            float cn = fmaf(F, c[q], I * Dd);
            float hn = O * tanhfast(cn);
            c[q] = cn; ph[q] = cn;
            // pack (h, h+1) pairs via neighbor lane; even-lr lanes store u32
            float co = __shfl_xor(cn, 1);
            float ho = __shfl_xor(hn, 1);
            if (!(lr & 1)) {
                const int batch = lg * 4 + q;
                char* bb = bufn + batch * 512;
                *(unsigned int*)(bb + ((2 * h) ^ ((batch & 7) << 4)))       = packh2(cn, co);
                *(unsigned int*)(bb + ((256 + 2 * h) ^ ((batch & 7) << 4))) = packh2(hn, ho);
            }
        }
        __syncthreads();
    }
    // ---- flush last step's history ----
    #pragma unroll
    for (int q = 0; q < 4; ++q) hp[q][0] = ph[q];
}

// 4096 blocks (b*64+s) x 256 threads. recur stashed c[b][s][0:128] in the first
// 512 B of this block's OWN 4 KB output region; read it, project, then overwrite
// the region with the projected row replicated 64x. No cross-block hazard.
__global__ __launch_bounds__(256) void proj_expand_k(const float* __restrict__ Wl,
                                                     const float* __restrict__ bl,
                                                     float* __restrict__ outb) {
    __shared__ float c_s[HDIM];
    __shared__ __align__(16) float pj[16];
    const int bs = blockIdx.x, t = threadIdx.x;
    float* reg = outb + (size_t)bs * 1024;
    if (t < HDIM) c_s[t] = reg[t];
    __syncthreads();
    if (t < 16) {
        float a = bl[t];
        #pragma unroll 16
        for (int h = 0; h < HDIM; ++h) a = fmaf(c_s[h], Wl[h * 16 + t], a);
        pj[t] = a;
    }
    __syncthreads();
    float4 v = ((const float4*)pj)[t & 3];
    ((float4*)reg)[t] = v;   // 256 float4 = 64 rows x 16 floats
}

extern "C" void kernel_launch(void* const* d_in, const int* in_sizes, int n_in,
                              void* d_out, int out_size, void* d_ws, size_t ws_size,
                              hipStream_t stream) {
    const float* trip = (const float*)d_in[0];
    // d_in[1] = valid_len : unused by the reference computation
    const float* emb  = (const float*)d_in[2];
    const float* Wg   = (const float*)d_in[3];
    const float* bgp  = (const float*)d_in[4];
    const float* Wlp  = (const float*)d_in[5];
    const float* blp  = (const float*)d_in[6];
    float* out = (float*)d_out;

    // output = [trip (262144 floats) | big (4194304 floats)]
    copy_trip_k<<<256, 256, 0, stream>>>((const float4*)trip, (float4*)out);
    recur_k<<<4, 512, 0, stream>>>(emb, Wg, bgp, out + 262144);
    proj_expand_k<<<4096, 256, 0, stream>>>(Wlp, blp, out + 262144);
}

// Round 9
// 90.206 us; speedup vs baseline: 1.3171x; 1.2534x over previous
//
#include <hip/hip_runtime.h>

typedef _Float16 f16x8 __attribute__((ext_vector_type(8)));
typedef float f32x4 __attribute__((ext_vector_type(4)));

#define HDIM  128
#define NSTEP 64
#define NG    512   // 4H gate columns
#define BPB   16    // batches per block (MFMA M)

#define LOG2E 1.44269504088896340736f

__device__ __forceinline__ float rcpf(float x) { return __builtin_amdgcn_rcpf(x); }
// 2^(-x), single v_exp_f32 with free input modifier
__device__ __forceinline__ float exp2neg(float x) {
    float r; asm("v_exp_f32 %0, -%1" : "=v"(r) : "v"(x)); return r;
}
__device__ __forceinline__ unsigned int packh2(float a, float b) {
    union { _Float16 h[2]; unsigned int u; } x;
    x.h[0] = (_Float16)a; x.h[1] = (_Float16)b; return x.u;
}

__global__ __launch_bounds__(256) void copy_trip_k(const float4* __restrict__ src,
                                                   float4* __restrict__ dst) {
    int i = blockIdx.x * 256 + threadIdx.x;   // 65536 float4 total
    dst[i] = src[i];
}

// grid = 4 blocks x 512 threads (8 waves). Block owns 16 batches.
// Wave w owns gate tiles {w, 8+w, 16+w, 24+w} = f,i,o,cand for h in
// [16w,16w+16): LSTM update is wave-local, one barrier/step.
// State layout: per batch, 128 words; word h = (c_h, h_h) f16 pair ->
// update writes ONE b32 per (batch,h), no shfl. k-map: k=2h -> c, k=2h+1 -> h;
// W rows permuted to match at load. W prescaled by log2e (cand 2log2e) so
// sigmoid/tanh use raw v_exp_f32 (exp2) with free -src modifier.
__global__ __launch_bounds__(512, 2) void recur_k(
    const float* __restrict__ emb, const float* __restrict__ Wg,
    const float* __restrict__ bg,  float* __restrict__ outb) {
    __shared__ __align__(16) unsigned int state_s[2][BPB * 128]; // 2 x 8KB

    const int blk = blockIdx.x, t = threadIdx.x;
    const int w = t >> 6, l = t & 63;
    const int lg = l >> 4, lr = l & 15;     // k-group, row-in-tile
    const int h = w * 16 + lr;              // h index this thread updates

    // ---- B-fragments + bias (one-time), prescaled; k = kt*32+lg*8+e;
    // input[k] = (k even) ? c[k/2] : h[k/2]  ->  W row = (k&1)?128+k/2:k/2 ----
    f16x8 B[4][8];
    f32x4 bias4[4];
    #pragma unroll
    for (int i = 0; i < 4; ++i) {
        const float sc = (i == 3) ? 2.f * LOG2E : LOG2E;
        const int c = i * 128 + h;
        const float bb = bg[c] * sc;
        bias4[i] = (f32x4){bb, bb, bb, bb};
        #pragma unroll
        for (int kt = 0; kt < 8; ++kt) {
            f16x8 v;
            #pragma unroll
            for (int e = 0; e < 8; ++e) {
                const int k = kt * 32 + lg * 8 + e;
                const int r = (k & 1) ? 128 + (k >> 1) : (k >> 1);
                v[e] = (_Float16)(Wg[r * NG + c] * sc);
            }
            B[i][kt] = v;
        }
    }
    #pragma unroll
    for (int i = 0; i < 4; ++i)
        #pragma unroll
        for (int kt = 0; kt < 8; ++kt)
            asm volatile("" : "+a"(B[i][kt]));   // materialize W in AGPRs

    // ---- initial state buf0: word h = (emb_h, 0) f16, XOR-swizzled ----
    for (int wd = t; wd < BPB * 128; wd += 512) {
        int batch = wd >> 7, kw = wd & 127;
        float ev = emb[(size_t)(blk * BPB + batch) * 64 * HDIM + kw];
        *(unsigned int*)((char*)state_s[0] + batch * 512 + ((kw * 4) ^ ((batch & 7) << 4)))
            = packh2(ev, 0.f);
    }
    float c[4] = {0.f, 0.f, 0.f, 0.f};   // c[batch=lg*4+q][h]
    float ph[4];                          // prev-step c (stored next step)
    int hoff[4];                          // constant lane offsets into outb
    #pragma unroll
    for (int q = 0; q < 4; ++q)
        hoff[q] = (blk * BPB + lg * 4 + q) * 65536 + h;
    __syncthreads();

    #pragma unroll 2
    for (int s = 0; s < NSTEP; ++s) {
        // ---- preload all 8 A-fragments (rows = batches) ----
        const char* buf = (const char*)state_s[s & 1];
        f16x8 a8[8];
        #pragma unroll
        for (int kt = 0; kt < 8; ++kt)
            a8[kt] = *(const f16x8*)(buf + lr * 512 + ((kt * 64 + lg * 16) ^ ((lr & 7) << 4)));
        // ---- pipelined history store (prev step), hidden under MFMA ----
        if (s > 0) {
            float* ob = outb + (size_t)(s - 1) * 1024;   // uniform base, saddr form
            #pragma unroll
            for (int q = 0; q < 4; ++q) ob[hoff[q]] = ph[q];
        }
        // ---- MFMA: acc[i] = gate tile (i*8+w); B from AGPRs, C=bias ----
        f32x4 acc[4];
        #pragma unroll
        for (int i = 0; i < 4; ++i)
            asm("v_mfma_f32_16x16x32_f16 %0, %1, %2, %3"
                : "=v"(acc[i]) : "v"(a8[0]), "a"(B[i][0]), "v"(bias4[i]));
        #pragma unroll
        for (int kt = 1; kt < 8; ++kt) {
            #pragma unroll
            for (int i = 0; i < 4; ++i)
                asm("v_mfma_f32_16x16x32_f16 %0, %1, %2, %0"
                    : "+v"(acc[i]) : "v"(a8[kt]), "a"(B[i][kt]));
        }
        // ---- wave-local update: thread owns (batch=lg*4+q, h), q=0..3 ----
        char* bufn = (char*)state_s[(s + 1) & 1];
        #pragma unroll
        for (int q = 0; q < 4; ++q) {
            float F = rcpf(1.f + exp2neg(acc[0][q]));
            float I = rcpf(1.f + exp2neg(acc[1][q]));
            float O = rcpf(1.f + exp2neg(acc[2][q]));
            float Dd = fmaf(2.f, rcpf(1.f + exp2neg(acc[3][q])), -1.f);
            float cn = fmaf(F, c[q], I * Dd);
            float th = fmaf(2.f, rcpf(1.f + exp2neg(cn * (2.f * LOG2E))), -1.f);
            float hn = O * th;
            c[q] = cn; ph[q] = cn;
            const int batch = lg * 4 + q;
            *(unsigned int*)(bufn + batch * 512 + ((4 * h) ^ ((batch & 7) << 4)))
                = packh2(cn, hn);
        }
        __syncthreads();
    }
    // ---- flush last step's history ----
    {
        float* ob = outb + (size_t)63 * 1024;
        #pragma unroll
        for (int q = 0; q < 4; ++q) ob[hoff[q]] = ph[q];
    }
}

// 4096 blocks (b*64+s) x 256 threads. recur stashed c[b][s][0:128] in the first
// 512 B of this block's OWN 4 KB output region; read it, project, then overwrite
// the region with the projected row replicated 64x. No cross-block hazard.
__global__ __launch_bounds__(256) void proj_expand_k(const float* __restrict__ Wl,
                                                     const float* __restrict__ bl,
                                                     float* __restrict__ outb) {
    __shared__ float c_s[HDIM];
    __shared__ __align__(16) float pj[16];
    const int bs = blockIdx.x, t = threadIdx.x;
    float* reg = outb + (size_t)bs * 1024;
    if (t < HDIM) c_s[t] = reg[t];
    __syncthreads();
    if (t < 16) {
        float a = bl[t];
        #pragma unroll 16
        for (int h = 0; h < HDIM; ++h) a = fmaf(c_s[h], Wl[h * 16 + t], a);
        pj[t] = a;
    }
    __syncthreads();
    float4 v = ((const float4*)pj)[t & 3];
    ((float4*)reg)[t] = v;   // 256 float4 = 64 rows x 16 floats
}

extern "C" void kernel_launch(void* const* d_in, const int* in_sizes, int n_in,
                              void* d_out, int out_size, void* d_ws, size_t ws_size,
                              hipStream_t stream) {
    const float* trip = (const float*)d_in[0];
    // d_in[1] = valid_len : unused by the reference computation
    const float* emb  = (const float*)d_in[2];
    const float* Wg   = (const float*)d_in[3];
    const float* bgp  = (const float*)d_in[4];
    const float* Wlp  = (const float*)d_in[5];
    const float* blp  = (const float*)d_in[6];
    float* out = (float*)d_out;

    // output = [trip (262144 floats) | big (4194304 floats)]
    copy_trip_k<<<256, 256, 0, stream>>>((const float4*)trip, (float4*)out);
    recur_k<<<4, 512, 0, stream>>>(emb, Wg, bgp, out + 262144);
    proj_expand_k<<<4096, 256, 0, stream>>>(Wlp, blp, out + 262144);
}

// Round 14
// 76.314 us; speedup vs baseline: 1.5569x; 1.1820x over previous
//
#include <hip/hip_runtime.h>

typedef _Float16 f16x8 __attribute__((ext_vector_type(8)));
typedef float f32x4 __attribute__((ext_vector_type(4)));

#define HDIM  128
#define NSTEP 64
#define NG    512   // 4H gate columns
#define NBLK  8     // recurrence blocks (CUs)
#define BPB   8     // batches per block

#define LOG2E 1.44269504088896340736f

__device__ __forceinline__ float rcpf(float x) { return __builtin_amdgcn_rcpf(x); }
// 2^(-x), single v_exp_f32 with free input modifier
__device__ __forceinline__ float exp2neg(float x) {
    float r; asm("v_exp_f32 %0, -%1" : "=v"(r) : "v"(x)); return r;
}
// round-to-nearest-even f16 pack
__device__ __forceinline__ unsigned int packh2(float a, float b) {
    union { _Float16 h[2]; unsigned int u; } x;
    x.h[0] = (_Float16)a; x.h[1] = (_Float16)b; return x.u;
}

// grid = 8 blocks x 512 threads (8 waves). Block owns 8 batches.
// A-operand MIRROR: a8 row = lr&7, so MFMA D rows 8-15 duplicate rows 0-7.
// Lane (lg,lr) then owns gates for batches b_base..b_base+1 in its OWN acc:
//   lg=0 -> batches 0,1 (q=0,1); lg=1 -> 4,5 (q=0,1);
//   lg=2 -> batches 2,3 (q=2,3); lg=3 -> 6,7 (q=2,3).
// -> NO cross-lane op touches the MFMA destination (the R9-R12 failure was
// introduced exactly when shfl_xor(acc) was added; R8's shfl-free update
// passed). State: per batch 128 words, word h = (c_h,h_h) f16, XOR-swizzled.
// W prescaled by log2e (cand 2log2e) -> raw v_exp_f32. W lives in AGPRs.
__global__ __launch_bounds__(512, 2) void recur_k(
    const float* __restrict__ emb, const float* __restrict__ Wg,
    const float* __restrict__ bg,  float* __restrict__ outb) {
    __shared__ __align__(16) unsigned int state_s[2][BPB * 128]; // 2 x 4KB

    const int blk = blockIdx.x, t = threadIdx.x;
    const int w = t >> 6, l = t & 63;
    const int lg = l >> 4, lr = l & 15;     // k-group, row-in-tile
    const int h = w * 16 + lr;              // h index this thread updates
    const int mr = lr & 7;                  // mirrored A-row (batch) this lane reads

    // ---- B-fragments + bias (one-time), prescaled; k = kt*32+lg*8+e;
    // input[k] = (k even) ? c[k/2] : h[k/2]  ->  W row = (k&1)?128+k/2:k/2 ----
    f16x8 B[4][8];
    f32x4 bias4[4];
    #pragma unroll
    for (int i = 0; i < 4; ++i) {
        const float sc = (i == 3) ? 2.f * LOG2E : LOG2E;
        const int c = i * 128 + h;
        const float bb = bg[c] * sc;
        bias4[i] = (f32x4){bb, bb, bb, bb};
        #pragma unroll
        for (int kt = 0; kt < 8; ++kt) {
            f16x8 v;
            #pragma unroll
            for (int e = 0; e < 8; ++e) {
                const int k = kt * 32 + lg * 8 + e;
                const int r = (k & 1) ? 128 + (k >> 1) : (k >> 1);
                v[e] = (_Float16)(Wg[r * NG + c] * sc);
            }
            B[i][kt] = v;
        }
    }
    #pragma unroll
    for (int i = 0; i < 4; ++i)
        #pragma unroll
        for (int kt = 0; kt < 8; ++kt)
            asm volatile("" : "+a"(B[i][kt]));   // materialize W in AGPRs

    // ---- initial state buf0: word kw of batch = (emb_kw, 0) f16 ----
    for (int wd = t; wd < BPB * 128; wd += 512) {
        int batch = wd >> 7, kw = wd & 127;
        float ev = emb[(size_t)(blk * BPB + batch) * 64 * HDIM + kw];
        *(unsigned int*)((char*)state_s[0] + batch * 512 + ((kw * 4) ^ ((batch & 7) << 4)))
            = packh2(ev, 0.f);
    }

    // update ownership (see header): batches b_base, b_base+1
    const int b_base = (lg & 1) * 4 + (lg >> 1) * 2;
    const bool hi = (lg >= 2);
    float c2[2] = {0.f, 0.f};
    float ph2[2];
    int hoff[2];
    #pragma unroll
    for (int j = 0; j < 2; ++j)
        hoff[j] = (blk * BPB + b_base + j) * 65536 + h;
    __syncthreads();

    #pragma unroll 2
    for (int s = 0; s < NSTEP; ++s) {
        // ---- preload all 8 A-fragments, mirrored row mr = lr&7 ----
        const char* buf = (const char*)state_s[s & 1];
        f16x8 a8[8];
        #pragma unroll
        for (int kt = 0; kt < 8; ++kt)
            a8[kt] = *(const f16x8*)(buf + mr * 512 + ((kt * 64 + lg * 16) ^ ((mr & 7) << 4)));
        // ---- pipelined history store (prev step), drains under MFMA ----
        if (s > 0) {
            float* ob = outb + (size_t)(s - 1) * 1024;
            #pragma unroll
            for (int j = 0; j < 2; ++j) ob[hoff[j]] = ph2[j];
        }
        // ---- MFMA: acc[i] = gate tile (i*8+w); tied in-place form ----
        f32x4 acc[4];
        #pragma unroll
        for (int i = 0; i < 4; ++i) acc[i] = bias4[i];
        asm volatile("s_nop 3");            // VALU mov -> MFMA SrcC spacing
        #pragma unroll
        for (int kt = 0; kt < 8; ++kt) {
            #pragma unroll
            for (int i = 0; i < 4; ++i)
                asm volatile("v_mfma_f32_16x16x32_f16 %0, %1, %2, %0"
                    : "+v"(acc[i]) : "v"(a8[kt]), "a"(B[i][kt]));
        }
        asm volatile("s_nop 7\n\ts_nop 7"); // MFMA -> VALU read spacing
        __builtin_amdgcn_sched_barrier(0);  // pin consumers after the nops
        // ---- dense update: 2 (batch,h) pairs per lane, own-acc select ----
        char* bufn = (char*)state_s[(s + 1) & 1];
        #pragma unroll
        for (int j = 0; j < 2; ++j) {
            const int qa = hi ? 2 + j : j;  // row (mirrored) holding batch b_base+j
            float F = rcpf(1.f + exp2neg(acc[0][qa]));
            float I = rcpf(1.f + exp2neg(acc[1][qa]));
            float O = rcpf(1.f + exp2neg(acc[2][qa]));
            float Dd = fmaf(2.f, rcpf(1.f + exp2neg(acc[3][qa])), -1.f);
            float cn = fmaf(F, c2[j], I * Dd);
            float th = fmaf(2.f, rcpf(1.f + exp2neg(cn * (2.f * LOG2E))), -1.f);
            float hn = O * th;
            c2[j] = cn; ph2[j] = cn;
            const int batch = b_base + j;
            *(unsigned int*)(bufn + batch * 512 + ((4 * h) ^ ((batch & 7) << 4)))
                = packh2(cn, hn);
        }
        __syncthreads();
    }
    // ---- flush last step's history ----
    {
        float* ob = outb + (size_t)63 * 1024;
        #pragma unroll
        for (int j = 0; j < 2; ++j) ob[hoff[j]] = ph2[j];
    }
}

// blocks 0..4095: (b*64+s) projection+expand. recur stashed c[b][s][0:128] in
// the first 512 B of this block's OWN 4 KB output region; read it, project,
// overwrite region with the projected row replicated 64x. No cross-block hazard.
// blocks 4096..4351: copy trip (1 MB) into the front of d_out.
__global__ __launch_bounds__(256) void proj_expand_k(const float* __restrict__ Wl,
                                                     const float* __restrict__ bl,
                                                     const float* __restrict__ trip,
                                                     float* __restrict__ trip_out,
                                                     float* __restrict__ outb) {
    const int bs = blockIdx.x, t = threadIdx.x;
    if (bs >= 4096) {   // trip copy: 256 blocks x 256 threads x 16 B
        int i = (bs - 4096) * 256 + t;
        ((float4*)trip_out)[i] = ((const float4*)trip)[i];
        return;
    }
    __shared__ float c_s[HDIM];
    __shared__ __align__(16) float pj[16];
    float* reg = outb + (size_t)bs * 1024;
    if (t < HDIM) c_s[t] = reg[t];
    __syncthreads();
    if (t < 16) {
        float a = bl[t];
        #pragma unroll 16
        for (int h = 0; h < HDIM; ++h) a = fmaf(c_s[h], Wl[h * 16 + t], a);
        pj[t] = a;
    }
    __syncthreads();
    float4 v = ((const float4*)pj)[t & 3];
    ((float4*)reg)[t] = v;   // 256 float4 = 64 rows x 16 floats
}

extern "C" void kernel_launch(void* const* d_in, const int* in_sizes, int n_in,
                              void* d_out, int out_size, void* d_ws, size_t ws_size,
                              hipStream_t stream) {
    const float* trip = (const float*)d_in[0];
    // d_in[1] = valid_len : unused by the reference computation
    const float* emb  = (const float*)d_in[2];
    const float* Wg   = (const float*)d_in[3];
    const float* bgp  = (const float*)d_in[4];
    const float* Wlp  = (const float*)d_in[5];
    const float* blp  = (const float*)d_in[6];
    float* out = (float*)d_out;

    // output = [trip (262144 floats) | big (4194304 floats)]
    recur_k<<<NBLK, 512, 0, stream>>>(emb, Wg, bgp, out + 262144);
    proj_expand_k<<<4096 + 256, 256, 0, stream>>>(Wlp, blp, trip, out, out + 262144);
}